// Round 5
// baseline (263.771 us; speedup 1.0000x reference)
//
#include <hip/hip_runtime.h>
#include <math.h>

// Problem constants
#define BB 32
#define CC 122
#define TT 500
#define SS 13
#define WID 80
#define EMB 8
#define PROJ 1024
#define HID 768
#define TP 96          // pooled time length
#define EPSF 1e-5f
#define KP 9760        // conv2 flat K' = 122*80
#define KBN 305        // KP/32 kb-iterations
#define KSPLIT 16

typedef float f32x4 __attribute__((ext_vector_type(4)));
typedef __bf16 bf16x8 __attribute__((ext_vector_type(8)));
typedef unsigned short u16x8 __attribute__((ext_vector_type(8)));
union BF8 { u16x8 u; bf16x8 b; };

// float -> bf16 bits, round-to-nearest-even
__device__ __forceinline__ unsigned short f2bf(float f) {
    union { float f; unsigned u; } v; v.f = f;
    unsigned r = v.u + 0x7FFFu + ((v.u >> 16) & 1u);
    return (unsigned short)(r >> 16);
}

// cheap ELU: hw v_exp; |err| ~1e-7, invisible vs bf16 noise
__device__ __forceinline__ float eluf(float x) {
    return x > 0.f ? x : __expf(x) - 1.f;
}

// ---------------- workspace layout (float offsets) ----------------
#define OFF_E    ((size_t)0)            // oute (B,C,T) f32        1,952,000
#define OFF_XB   ((size_t)1952000)      // x_bf (B,128,512) bf16 -> 1,048,576 f
#define OFF_WB   ((size_t)3000576)      // W_bf (S,512,512) bf16 -> 1,703,936 f
#define OFF_W2P  ((size_t)4704512)      // w2p (80,9760) bf16    ->   390,400 f
#define OFF_P    ((size_t)5094912)      // p (B,96,9760) bf16    ->14,991,360 f
#define OFF_PART ((size_t)20086272)     // (KS,B,WID,TP) f32       3,932,160
#define OFF_Z    ((size_t)24018432)     // z_bf (B,HID) bf16          12,288 f
#define OFF_Z1   ((size_t)24043008)     // (B,PROJ) f32               32,768
#define OFF_G    ((size_t)24075776)     // g_bf (B,PROJ) bf16         16,384 f
#define OFF_Y    ((size_t)24108544)     // (B,PROJ) f32               32,768
#define OFF_WC   ((size_t)24141312)     // (WID,21)                    1,680
#define OFF_B1F  ((size_t)24142992)     // (WID)                          80
#define OFF_SC2  ((size_t)24143072)     // (WID)                          80
#define OFF_SH2  ((size_t)24143152)     // (WID)                          80
#define OFF_BAR  ((size_t)24143232)     // 8 x u32 grid-barrier counters

// pack region sizes (elements)
#define NPK_X  (2097152)   // 32*128*512
#define NPK_W  (3407872)   // 13*512*512
#define NPK_W2 (780800)    // 80*9760
#define NPK_TOT (NPK_X + NPK_W + NPK_W2)

// ---------------- pack (bf16 staging) + prep + barrier zero (block 0) ----------------
__global__ __launch_bounds__(256) void k_pack(const float* __restrict__ x,
                                              const float* __restrict__ W_sub,
                                              const float* __restrict__ conv2_w,
                                              const float* __restrict__ conv1_w, const float* __restrict__ conv1_b,
                                              const float* __restrict__ g1, const float* __restrict__ b1,
                                              const float* __restrict__ m1, const float* __restrict__ v1,
                                              const float* __restrict__ conv2_b, const float* __restrict__ g2,
                                              const float* __restrict__ b2, const float* __restrict__ m2,
                                              const float* __restrict__ v2,
                                              unsigned short* __restrict__ xb,
                                              unsigned short* __restrict__ wb,
                                              unsigned short* __restrict__ w2p,
                                              float* __restrict__ wc2, float* __restrict__ bias1f,
                                              float* __restrict__ scale2, float* __restrict__ shift2f,
                                              unsigned* __restrict__ bar) {
    if (blockIdx.x == 0) {
        int o = threadIdx.x;
        if (o < 8) bar[o] = 0u;   // zero grid-barrier counters EVERY launch (ws is poisoned)
        if (o < WID) {
            float s1 = g1[o] * rsqrtf(v1[o] + EPSF);
            float sh1 = b1[o] - m1[o] * s1;
            #pragma unroll
            for (int d = 0; d < 21; d++) {
                int klo = d - 16; if (klo < 0) klo = 0;
                int khi = d;      if (khi > 4) khi = 4;
                float acc = 0.f;
                for (int k = klo; k <= khi; k++) acc += conv1_w[o*5 + k];
                wc2[o*21 + d] = acc * s1 * (1.f/17.f);
            }
            bias1f[o] = conv1_b[o] * s1 + sh1;
            float s2 = g2[o] * rsqrtf(v2[o] + EPSF);
            scale2[o] = s2;
            shift2f[o] = conv2_b[o] * s2 + (b2[o] - m2[o] * s2);
        }
    }
    size_t idx = (size_t)blockIdx.x * 256 + threadIdx.x;
    if (idx >= (size_t)NPK_TOT) return;
    if (idx < NPK_X) {
        int s = idx & 511, c = (idx >> 9) & 127, b = idx >> 16;
        float v = (c < CC && s < TT) ? x[((size_t)b * CC + c) * TT + s] : 0.f;
        xb[idx] = f2bf(v);
    } else if (idx < NPK_X + NPK_W) {
        size_t j = idx - NPK_X;
        int s = j & 511, t = (j >> 9) & 511, sub = j >> 18;
        float v = (t < TT && s < TT) ? W_sub[((size_t)sub * TT + t) * TT + s] : 0.f;
        wb[j] = f2bf(v);
    } else {
        size_t j = idx - NPK_X - NPK_W;
        int o = (int)(j / KP);
        int k = (int)(j % KP);
        int c = k / WID, op = k % WID;
        float v = conv2_w[((size_t)(o * WID + op)) * CC + c];
        w2p[j] = f2bf(v);
    }
}

// ---------------- subject einsum via MFMA bf16 ----------------
__global__ __launch_bounds__(256) void k_einsum(const unsigned short* __restrict__ xb,
                                                const unsigned short* __restrict__ wb,
                                                const int* __restrict__ sid,
                                                const float* __restrict__ b_sub,
                                                float* __restrict__ oute) {
    int t0 = blockIdx.x * 64, b = blockIdx.y;
    int s = sid[b];
    int tid = threadIdx.x, w = tid >> 6, lr = tid & 15, lg = (tid >> 4) & 3;
    const unsigned short* A0 = xb + ((size_t)(b * 128 + w * 32 + lr)) * 512 + 8 * lg;
    const unsigned short* Bb = wb + (size_t)s * 262144 + 8 * lg;
    f32x4 acc[2][4] = {};
    for (int kb = 0; kb < 512; kb += 32) {
        BF8 a0, a1;
        a0.u = *(const u16x8*)(A0 + kb);
        a1.u = *(const u16x8*)(A0 + 16 * 512 + kb);
        #pragma unroll
        for (int nt = 0; nt < 4; nt++) {
            BF8 bf; bf.u = *(const u16x8*)(Bb + (size_t)(t0 + nt * 16 + lr) * 512 + kb);
            acc[0][nt] = __builtin_amdgcn_mfma_f32_16x16x32_bf16(a0.b, bf.b, acc[0][nt], 0, 0, 0);
            acc[1][nt] = __builtin_amdgcn_mfma_f32_16x16x32_bf16(a1.b, bf.b, acc[1][nt], 0, 0, 0);
        }
    }
    const float* bg = b_sub + (size_t)s * TT;
    #pragma unroll
    for (int nt = 0; nt < 4; nt++) {
        int t = t0 + nt * 16 + lr;
        if (t < TT) {
            float bias = bg[t];
            #pragma unroll
            for (int mt = 0; mt < 2; mt++) {
                int crow = w * 32 + mt * 16 + 4 * lg;
                #pragma unroll
                for (int r = 0; r < 4; r++) {
                    int c = crow + r;
                    if (c < CC) oute[((size_t)b * CC + c) * TT + t] = acc[mt][nt][r] + bias;
                }
            }
        }
    }
}

// ---------------- FIR21 stride5 + bn1 + elu -> p[b][t][c*80+o'] bf16 ----------------
__global__ __launch_bounds__(256, 2) void k_fir(const float* __restrict__ oute,
                                                const float* __restrict__ wc2,
                                                const float* __restrict__ b1f,
                                                unsigned short* __restrict__ p) {
    __shared__ float e_lds[TT];
    int c = blockIdx.x, b = blockIdx.y;
    int tid = threadIdx.x;
    if (tid < 125)
        ((float4*)e_lds)[tid] = ((const float4*)(oute + ((size_t)b * CC + c) * TT))[tid];
    __syncthreads();
    if (tid >= 240) return;
    int po = tid % WID, third = tid / WID;
    float wcr[21];
    #pragma unroll
    for (int d = 0; d < 21; d++) wcr[d] = wc2[po * 21 + d];
    float pbias = b1f[po];
    int tbase = third * 32;
    unsigned short* prow = p + ((size_t)b * TP) * KP + (size_t)c * WID + po;
    #pragma unroll 2
    for (int g = 0; g < 8; g++) {
        const float4* ep = (const float4*)(e_lds + tbase * 5 + 20 * g);
        float4 q0 = ep[0], q1 = ep[1], q2 = ep[2], q3 = ep[3], q4 = ep[4],
               q5 = ep[5], q6 = ep[6], q7 = ep[7], q8 = ep[8];
        float wv[36] = {q0.x,q0.y,q0.z,q0.w, q1.x,q1.y,q1.z,q1.w,
                        q2.x,q2.y,q2.z,q2.w, q3.x,q3.y,q3.z,q3.w,
                        q4.x,q4.y,q4.z,q4.w, q5.x,q5.y,q5.z,q5.w,
                        q6.x,q6.y,q6.z,q6.w, q7.x,q7.y,q7.z,q7.w,
                        q8.x,q8.y,q8.z,q8.w};
        #pragma unroll
        for (int j = 0; j < 4; j++) {
            float a = pbias;
            #pragma unroll
            for (int d = 0; d < 21; d++) a = fmaf(wcr[d], wv[5*j + d], a);
            a = eluf(a);
            prow[(size_t)(tbase + 4*g + j) * KP] = f2bf(a);
        }
    }
}

// ---------------- conv2 pure MFMA GEMM ----------------
__global__ __launch_bounds__(384) void k_conv2(const unsigned short* __restrict__ p,
                                               const unsigned short* __restrict__ w2p,
                                               float* __restrict__ part) {
    int chunk = blockIdx.x, b = blockIdx.y;
    int tid = threadIdx.x, w = tid >> 6, l = tid & 63, lr = l & 15, lg = l >> 4;
    int kb0 = (chunk * KBN) / KSPLIT;
    int kb1 = ((chunk + 1) * KBN) / KSPLIT;
    const unsigned short* Brow = p + ((size_t)(b * TP + w * 16 + lr)) * KP + 8 * lg;
    const unsigned short* Arow = w2p + (size_t)lr * KP + 8 * lg;
    f32x4 acc[5] = {};
    for (int kb = kb0; kb < kb1; kb++) {
        int ko = kb * 32;
        BF8 bf; bf.u = *(const u16x8*)(Brow + ko);
        #pragma unroll
        for (int mt = 0; mt < 5; mt++) {
            BF8 af; af.u = *(const u16x8*)(Arow + (size_t)mt * 16 * KP + ko);
            acc[mt] = __builtin_amdgcn_mfma_f32_16x16x32_bf16(af.b, bf.b, acc[mt], 0, 0, 0);
        }
    }
    float* pp = part + ((size_t)(chunk * BB + b) * WID) * TP;
    int t = w * 16 + lr;
    #pragma unroll
    for (int mt = 0; mt < 5; mt++) {
        int ob = mt * 16 + 4 * lg;
        #pragma unroll
        for (int r = 0; r < 4; r++)
            pp[(size_t)(ob + r) * TP + t] = acc[mt][r];
    }
}

// ---------------- grid barrier (device-scope; 32 co-resident blocks) ----------------
__device__ __forceinline__ void gbarrier(unsigned* ctr) {
    __threadfence();          // release this thread's global writes (device scope)
    __syncthreads();          // all threads of block fenced before arrival
    if (threadIdx.x == 0) {
        atomicAdd(ctr, 1u);   // device-scope by default (m20)
        while (atomicAdd(ctr, 0u) < BB) {}
    }
    __syncthreads();
    __threadfence();          // acquire: invalidate stale cache before reading others' data
}

// ---------------- fused tail: reduce+bn2+elu+proj -> mlp1+gelu -> mlp2+res -> LN ----
// 32 blocks x 256 thr, 3 grid barriers. Phases 1/2 reinterpret blockIdx as col-block.
__global__ __launch_bounds__(256) void k_tail(const float* __restrict__ part,
                                              const float* __restrict__ scale2,
                                              const float* __restrict__ shift2f,
                                              const float* __restrict__ pw,
                                              const float* __restrict__ pb,
                                              const float* __restrict__ w1,
                                              const float* __restrict__ b1m,
                                              const float* __restrict__ w2m,
                                              const float* __restrict__ b2m,
                                              const float* __restrict__ lg_,
                                              const float* __restrict__ lb_,
                                              unsigned short* __restrict__ zbf,
                                              float* __restrict__ z1,
                                              unsigned short* __restrict__ gbf,
                                              float* __restrict__ y,
                                              float* __restrict__ out,
                                              unsigned* __restrict__ bar) {
    __shared__ float ly[WID * TP];   // 7680 f
    __shared__ float lw[EMB * WID];  // 640 f
    int tid = threadIdx.x;

    // ---- phase 0: split-K reduce + bn2 + elu (LDS) + proj -> zbf[32,768]
    {
        int b = blockIdx.x;
        for (int i = tid; i < EMB * WID; i += 256) lw[i] = pw[i];
        for (int i = tid; i < WID * TP; i += 256) {
            float acc = 0.f;
            #pragma unroll
            for (int ks = 0; ks < KSPLIT; ks++)
                acc += part[(size_t)(ks * BB + b) * (WID * TP) + i];
            int o = i / TP;
            ly[i] = eluf(acc * scale2[o] + shift2f[o]);
        }
        __syncthreads();
        #pragma unroll
        for (int rep = 0; rep < 3; rep++) {
            int j = tid + 256 * rep;
            int e = j & 7, t = j >> 3;
            float acc = pb[e];
            #pragma unroll 10
            for (int o = 0; o < WID; o++) acc = fmaf(ly[o * TP + t], lw[e * WID + o], acc);
            zbf[(size_t)b * HID + j] = f2bf(acc);
        }
    }
    gbarrier(bar + 0);

    // ---- phase 1: z1[32,1024] = Zbf @ W1^T + b1m; gbf = gelu(z1)
    // block j -> pcols j*32..+31; wave w: n-tile (w&1), m-tile (w>>1)
    {
        int w = tid >> 6, lr = tid & 15, lg = (tid >> 4) & 3;
        int nt = w & 1, mt = w >> 1;
        int pcol = blockIdx.x * 32 + nt * 16 + lr;
        const float* wr = w1 + (size_t)pcol * HID + 8 * lg;
        const unsigned short* za = zbf + (size_t)(mt * 16 + lr) * HID + 8 * lg;
        f32x4 acc = {};
        for (int kb = 0; kb < HID; kb += 32) {
            float4 w0 = *(const float4*)(wr + kb);
            float4 w1v = *(const float4*)(wr + kb + 4);
            BF8 bf;
            bf.u[0] = f2bf(w0.x); bf.u[1] = f2bf(w0.y); bf.u[2] = f2bf(w0.z); bf.u[3] = f2bf(w0.w);
            bf.u[4] = f2bf(w1v.x); bf.u[5] = f2bf(w1v.y); bf.u[6] = f2bf(w1v.z); bf.u[7] = f2bf(w1v.w);
            BF8 a; a.u = *(const u16x8*)(za + kb);
            acc = __builtin_amdgcn_mfma_f32_16x16x32_bf16(a.b, bf.b, acc, 0, 0, 0);
        }
        float bs = b1m[pcol];
        #pragma unroll
        for (int r = 0; r < 4; r++) {
            int bb = mt * 16 + 4 * lg + r;
            float v = acc[r] + bs;
            z1[(size_t)bb * PROJ + pcol] = v;
            gbf[(size_t)bb * PROJ + pcol] = f2bf(0.5f * v * (1.f + erff(v * 0.70710678118654752f)));
        }
    }
    gbarrier(bar + 1);

    // ---- phase 2: y = z1 + Gbf @ W2m^T + b2m
    {
        int w = tid >> 6, lr = tid & 15, lg = (tid >> 4) & 3;
        int nt = w & 1, mt = w >> 1;
        int q = blockIdx.x * 32 + nt * 16 + lr;
        const float* wr = w2m + (size_t)q * PROJ + 8 * lg;
        const unsigned short* ga = gbf + (size_t)(mt * 16 + lr) * PROJ + 8 * lg;
        f32x4 acc = {};
        for (int kb = 0; kb < PROJ; kb += 32) {
            float4 w0 = *(const float4*)(wr + kb);
            float4 w1v = *(const float4*)(wr + kb + 4);
            BF8 bf;
            bf.u[0] = f2bf(w0.x); bf.u[1] = f2bf(w0.y); bf.u[2] = f2bf(w0.z); bf.u[3] = f2bf(w0.w);
            bf.u[4] = f2bf(w1v.x); bf.u[5] = f2bf(w1v.y); bf.u[6] = f2bf(w1v.z); bf.u[7] = f2bf(w1v.w);
            BF8 a; a.u = *(const u16x8*)(ga + kb);
            acc = __builtin_amdgcn_mfma_f32_16x16x32_bf16(a.b, bf.b, acc, 0, 0, 0);
        }
        float bs = b2m[q];
        #pragma unroll
        for (int r = 0; r < 4; r++) {
            int bb = mt * 16 + 4 * lg + r;
            y[(size_t)bb * PROJ + q] = z1[(size_t)bb * PROJ + q] + acc[r] + bs;
        }
    }
    gbarrier(bar + 2);

    // ---- phase 3: LayerNorm row b -> out
    {
        int b = blockIdx.x;
        const float4* yr = (const float4*)(y + (size_t)b * PROJ);
        float4 v = yr[tid];
        float s  = v.x + v.y + v.z + v.w;
        float sq = v.x*v.x + v.y*v.y + v.z*v.z + v.w*v.w;
        #pragma unroll
        for (int off = 32; off > 0; off >>= 1) {
            s  += __shfl_down(s, off);
            sq += __shfl_down(sq, off);
        }
        __shared__ float ss[4], ssq[4];
        __shared__ float smu, sinv;
        int wv = tid >> 6, lane = tid & 63;
        if (lane == 0) { ss[wv] = s; ssq[wv] = sq; }
        __syncthreads();
        if (tid == 0) {
            float Sm = ss[0] + ss[1] + ss[2] + ss[3];
            float Sq = ssq[0] + ssq[1] + ssq[2] + ssq[3];
            float mu = Sm * (1.f / PROJ);
            float var = Sq * (1.f / PROJ) - mu * mu;
            smu = mu;
            sinv = rsqrtf(var + EPSF);
        }
        __syncthreads();
        float mu = smu, inv = sinv;
        float4 g4 = ((const float4*)lg_)[tid];
        float4 b4 = ((const float4*)lb_)[tid];
        float4 o4;
        o4.x = (v.x - mu) * inv * g4.x + b4.x;
        o4.y = (v.y - mu) * inv * g4.y + b4.y;
        o4.z = (v.z - mu) * inv * g4.z + b4.z;
        o4.w = (v.w - mu) * inv * g4.w + b4.w;
        ((float4*)(out + (size_t)b * PROJ))[tid] = o4;
    }
}

extern "C" void kernel_launch(void* const* d_in, const int* in_sizes, int n_in,
                              void* d_out, int out_size, void* d_ws, size_t ws_size,
                              hipStream_t stream) {
    const float* x        = (const float*)d_in[0];
    const int*   sid      = (const int*)  d_in[1];
    const float* W_sub    = (const float*)d_in[2];
    const float* b_sub    = (const float*)d_in[3];
    const float* conv1_w  = (const float*)d_in[4];
    const float* conv1_b  = (const float*)d_in[5];
    const float* bn1_g    = (const float*)d_in[6];
    const float* bn1_b    = (const float*)d_in[7];
    const float* bn1_m    = (const float*)d_in[8];
    const float* bn1_v    = (const float*)d_in[9];
    const float* conv2_w  = (const float*)d_in[10];
    const float* conv2_b  = (const float*)d_in[11];
    const float* bn2_g    = (const float*)d_in[12];
    const float* bn2_b    = (const float*)d_in[13];
    const float* bn2_m    = (const float*)d_in[14];
    const float* bn2_v    = (const float*)d_in[15];
    const float* proj_w   = (const float*)d_in[16];
    const float* proj_b   = (const float*)d_in[17];
    const float* mlp1_w   = (const float*)d_in[18];
    const float* mlp1_b   = (const float*)d_in[19];
    const float* mlp2_w   = (const float*)d_in[20];
    const float* mlp2_b   = (const float*)d_in[21];
    const float* ln_g     = (const float*)d_in[22];
    const float* ln_b     = (const float*)d_in[23];
    float* out = (float*)d_out;
    float* ws  = (float*)d_ws;

    float* ws_e    = ws + OFF_E;
    unsigned short* ws_xb  = (unsigned short*)(ws + OFF_XB);
    unsigned short* ws_wb  = (unsigned short*)(ws + OFF_WB);
    unsigned short* ws_w2p = (unsigned short*)(ws + OFF_W2P);
    unsigned short* ws_p   = (unsigned short*)(ws + OFF_P);
    float* ws_part = ws + OFF_PART;
    unsigned short* ws_zbf = (unsigned short*)(ws + OFF_Z);
    float* ws_z1   = ws + OFF_Z1;
    unsigned short* ws_gbf = (unsigned short*)(ws + OFF_G);
    float* ws_y    = ws + OFF_Y;
    float* ws_wc   = ws + OFF_WC;
    float* ws_b1f  = ws + OFF_B1F;
    float* ws_sc2  = ws + OFF_SC2;
    float* ws_sh2  = ws + OFF_SH2;
    unsigned* ws_bar = (unsigned*)(ws + OFF_BAR);

    hipLaunchKernelGGL(k_pack, dim3((NPK_TOT + 255) / 256), dim3(256), 0, stream,
                       x, W_sub, conv2_w,
                       conv1_w, conv1_b, bn1_g, bn1_b, bn1_m, bn1_v,
                       conv2_b, bn2_g, bn2_b, bn2_m, bn2_v,
                       ws_xb, ws_wb, ws_w2p,
                       ws_wc, ws_b1f, ws_sc2, ws_sh2, ws_bar);

    hipLaunchKernelGGL(k_einsum, dim3(8, BB), dim3(256), 0, stream,
                       ws_xb, ws_wb, sid, b_sub, ws_e);

    hipLaunchKernelGGL(k_fir, dim3(CC, BB), dim3(256), 0, stream,
                       ws_e, ws_wc, ws_b1f, ws_p);

    hipLaunchKernelGGL(k_conv2, dim3(KSPLIT, BB), dim3(384), 0, stream,
                       ws_p, ws_w2p, ws_part);

    hipLaunchKernelGGL(k_tail, dim3(BB), dim3(256), 0, stream,
                       ws_part, ws_sc2, ws_sh2, proj_w, proj_b,
                       mlp1_w, mlp1_b, mlp2_w, mlp2_b, ln_g, ln_b,
                       ws_zbf, ws_z1, ws_gbf, ws_y, out, ws_bar);
}

// Round 6
// 244.630 us; speedup vs baseline: 1.0782x; 1.0782x over previous
//
#include <hip/hip_runtime.h>
#include <math.h>

// Problem constants
#define BB 32
#define CC 122
#define TT 500
#define SS 13
#define WID 80
#define EMB 8
#define PROJ 1024
#define HID 768
#define TP 96          // pooled time length
#define EPSF 1e-5f
#define KP 9760        // conv2 flat K' = 122*80
#define KBN 305        // KP/32 kb-iterations
#define KSPLIT 16

typedef float f32x4 __attribute__((ext_vector_type(4)));
typedef __bf16 bf16x8 __attribute__((ext_vector_type(8)));
typedef unsigned short u16x8 __attribute__((ext_vector_type(8)));
union BF8 { u16x8 u; bf16x8 b; };

// float -> bf16 bits, round-to-nearest-even
__device__ __forceinline__ unsigned short f2bf(float f) {
    union { float f; unsigned u; } v; v.f = f;
    unsigned r = v.u + 0x7FFFu + ((v.u >> 16) & 1u);
    return (unsigned short)(r >> 16);
}

// cheap ELU: hw v_exp; |err| ~1e-7, invisible vs bf16 noise
__device__ __forceinline__ float eluf(float x) {
    return x > 0.f ? x : __expf(x) - 1.f;
}

// ---------------- workspace layout (float offsets) ----------------
#define OFF_E    ((size_t)0)            // oute (B,C,T) f32        1,952,000
#define OFF_XB   ((size_t)1952000)      // x_bf (B,128,512) bf16 -> 1,048,576 f
#define OFF_WB   ((size_t)3000576)      // W_bf (S,512,512) bf16 -> 1,703,936 f
#define OFF_W2P  ((size_t)4704512)      // w2p (80,9760) bf16    ->   390,400 f
#define OFF_P    ((size_t)5094912)      // p (B,96,9760) bf16    ->14,991,360 f
#define OFF_PART ((size_t)20086272)     // (KS,B,WID,TP) f32       3,932,160
#define OFF_Z    ((size_t)24018432)     // z_bf (B,HID) bf16          12,288 f
#define OFF_Z1   ((size_t)24043008)     // (B,PROJ) f32               32,768
#define OFF_G    ((size_t)24075776)     // g_bf (B,PROJ) bf16         16,384 f
#define OFF_Y    ((size_t)24108544)     // (B,PROJ) f32               32,768
#define OFF_WCB  ((size_t)24141312)     // wcb (80,32) bf16 ->         1,280 f
#define OFF_B1F  ((size_t)24142992)     // (WID)                          80
#define OFF_SC2  ((size_t)24143072)     // (WID)                          80
#define OFF_SH2  ((size_t)24143152)     // (WID)                          80

// pack region sizes (elements)
#define NPK_X  (2097152)   // 32*128*512
#define NPK_W  (3407872)   // 13*512*512
#define NPK_W2 (780800)    // 80*9760
#define NPK_TOT (NPK_X + NPK_W + NPK_W2)

// ---------------- pack (bf16 staging) + prep (block 0) ----------------
__global__ __launch_bounds__(256) void k_pack(const float* __restrict__ x,
                                              const float* __restrict__ W_sub,
                                              const float* __restrict__ conv2_w,
                                              const float* __restrict__ conv1_w, const float* __restrict__ conv1_b,
                                              const float* __restrict__ g1, const float* __restrict__ b1,
                                              const float* __restrict__ m1, const float* __restrict__ v1,
                                              const float* __restrict__ conv2_b, const float* __restrict__ g2,
                                              const float* __restrict__ b2, const float* __restrict__ m2,
                                              const float* __restrict__ v2,
                                              unsigned short* __restrict__ xb,
                                              unsigned short* __restrict__ wb,
                                              unsigned short* __restrict__ w2p,
                                              unsigned short* __restrict__ wcb, float* __restrict__ bias1f,
                                              float* __restrict__ scale2, float* __restrict__ shift2f) {
    if (blockIdx.x == 0) {
        int o = threadIdx.x;
        if (o < WID) {
            float s1 = g1[o] * rsqrtf(v1[o] + EPSF);
            float sh1 = b1[o] - m1[o] * s1;
            // folded conv1(5-tap)+avgpool(17,5)+bn1 -> 21-tap filter bank, bf16, K-padded to 32
            #pragma unroll
            for (int d = 0; d < 21; d++) {
                int klo = d - 16; if (klo < 0) klo = 0;
                int khi = d;      if (khi > 4) khi = 4;
                float acc = 0.f;
                for (int k = klo; k <= khi; k++) acc += conv1_w[o*5 + k];
                wcb[o*32 + d] = f2bf(acc * s1 * (1.f/17.f));
            }
            #pragma unroll
            for (int d = 21; d < 32; d++) wcb[o*32 + d] = 0;
            bias1f[o] = conv1_b[o] * s1 + sh1;
            float s2 = g2[o] * rsqrtf(v2[o] + EPSF);
            scale2[o] = s2;
            shift2f[o] = conv2_b[o] * s2 + (b2[o] - m2[o] * s2);
        }
    }
    size_t idx = (size_t)blockIdx.x * 256 + threadIdx.x;
    if (idx >= (size_t)NPK_TOT) return;
    if (idx < NPK_X) {
        int s = idx & 511, c = (idx >> 9) & 127, b = idx >> 16;
        float v = (c < CC && s < TT) ? x[((size_t)b * CC + c) * TT + s] : 0.f;
        xb[idx] = f2bf(v);
    } else if (idx < NPK_X + NPK_W) {
        size_t j = idx - NPK_X;
        int s = j & 511, t = (j >> 9) & 511, sub = j >> 18;
        float v = (t < TT && s < TT) ? W_sub[((size_t)sub * TT + t) * TT + s] : 0.f;
        wb[j] = f2bf(v);
    } else {
        size_t j = idx - NPK_X - NPK_W;
        int o = (int)(j / KP);
        int k = (int)(j % KP);
        int c = k / WID, op = k % WID;
        float v = conv2_w[((size_t)(o * WID + op)) * CC + c];
        w2p[j] = f2bf(v);
    }
}

// ---------------- subject einsum via MFMA bf16 ----------------
__global__ __launch_bounds__(256) void k_einsum(const unsigned short* __restrict__ xb,
                                                const unsigned short* __restrict__ wb,
                                                const int* __restrict__ sid,
                                                const float* __restrict__ b_sub,
                                                float* __restrict__ oute) {
    int t0 = blockIdx.x * 64, b = blockIdx.y;
    int s = sid[b];
    int tid = threadIdx.x, w = tid >> 6, lr = tid & 15, lg = (tid >> 4) & 3;
    const unsigned short* A0 = xb + ((size_t)(b * 128 + w * 32 + lr)) * 512 + 8 * lg;
    const unsigned short* Bb = wb + (size_t)s * 262144 + 8 * lg;
    f32x4 acc[2][4] = {};
    for (int kb = 0; kb < 512; kb += 32) {
        BF8 a0, a1;
        a0.u = *(const u16x8*)(A0 + kb);
        a1.u = *(const u16x8*)(A0 + 16 * 512 + kb);
        #pragma unroll
        for (int nt = 0; nt < 4; nt++) {
            BF8 bf; bf.u = *(const u16x8*)(Bb + (size_t)(t0 + nt * 16 + lr) * 512 + kb);
            acc[0][nt] = __builtin_amdgcn_mfma_f32_16x16x32_bf16(a0.b, bf.b, acc[0][nt], 0, 0, 0);
            acc[1][nt] = __builtin_amdgcn_mfma_f32_16x16x32_bf16(a1.b, bf.b, acc[1][nt], 0, 0, 0);
        }
    }
    const float* bg = b_sub + (size_t)s * TT;
    #pragma unroll
    for (int nt = 0; nt < 4; nt++) {
        int t = t0 + nt * 16 + lr;
        if (t < TT) {
            float bias = bg[t];
            #pragma unroll
            for (int mt = 0; mt < 2; mt++) {
                int crow = w * 32 + mt * 16 + 4 * lg;
                #pragma unroll
                for (int r = 0; r < 4; r++) {
                    int c = crow + r;
                    if (c < CC) oute[((size_t)b * CC + c) * TT + t] = acc[mt][nt][r] + bias;
                }
            }
        }
    }
}

// ---------------- FIR via MFMA: p[b][t][c*80+o] = elu(FIR21(e) + b1f), bf16 ----------------
// A = wcb filter bank (5 o-tiles, preloaded in regs), B = window frags from e in LDS
// (lane t=lr, k=8*lg+j -> e[5t+k]; taps 21..31 are zero so padded e[500..511]=0 is safe).
// D rows = o => each lane's 4 acc values are 4 consecutive o => packed 8B stores.
// grid (61 c-pairs, 32 b), 256 thr = 4 waves; 12 units (2c x 6 t-tiles), 3 per wave.
__global__ __launch_bounds__(256) void k_fir2(const float* __restrict__ oute,
                                              const unsigned short* __restrict__ wcb,
                                              const float* __restrict__ b1f,
                                              unsigned short* __restrict__ p) {
    __shared__ float e2[2][512];
    int cp = blockIdx.x, b = blockIdx.y;
    int tid = threadIdx.x;
    int w = tid >> 6, lr = tid & 15, lg = (tid >> 4) & 3;
    if (tid < 250) {
        int cc = tid / 125, i = tid % 125;
        ((float4*)e2[cc])[i] = ((const float4*)(oute + ((size_t)b * CC + cp * 2 + cc) * TT))[i];
    }
    if (tid >= 232) {                  // zero-pad e[500..511] both rows
        int j = tid - 232; int cc = j / 12, i = 500 + (j % 12);
        e2[cc][i] = 0.f;
    }
    BF8 af[5]; float4 bf4[5];
    #pragma unroll
    for (int ot = 0; ot < 5; ot++) {
        af[ot].u = *(const u16x8*)(wcb + (ot * 16 + lr) * 32 + 8 * lg);
        bf4[ot] = *(const float4*)(b1f + ot * 16 + 4 * lg);
    }
    __syncthreads();
    #pragma unroll
    for (int ui = 0; ui < 3; ui++) {
        int u = w + 4 * ui;            // 0..11, each exactly once across 4 waves
        int cc = u / 6, tt = u % 6;
        int t = tt * 16 + lr;
        const float* ew = e2[cc] + 5 * t + 8 * lg;
        BF8 bfr;
        #pragma unroll
        for (int j = 0; j < 8; j++) bfr.u[j] = f2bf(ew[j]);
        f32x4 acc[5] = {};
        #pragma unroll
        for (int ot = 0; ot < 5; ot++)
            acc[ot] = __builtin_amdgcn_mfma_f32_16x16x32_bf16(af[ot].b, bfr.b, acc[ot], 0, 0, 0);
        int c = cp * 2 + cc;
        unsigned short* pr = p + ((size_t)b * TP + t) * KP + (size_t)c * WID + 4 * lg;
        #pragma unroll
        for (int ot = 0; ot < 5; ot++) {
            union { unsigned short s[4]; uint2 v; } pk;
            #pragma unroll
            for (int r = 0; r < 4; r++) pk.s[r] = f2bf(eluf(acc[ot][r] + bf4[ot][r]));
            *(uint2*)(pr + ot * 16) = pk.v;
        }
    }
}

// ---------------- conv2 pure MFMA GEMM ----------------
__global__ __launch_bounds__(384) void k_conv2(const unsigned short* __restrict__ p,
                                               const unsigned short* __restrict__ w2p,
                                               float* __restrict__ part) {
    int chunk = blockIdx.x, b = blockIdx.y;
    int tid = threadIdx.x, w = tid >> 6, l = tid & 63, lr = l & 15, lg = l >> 4;
    int kb0 = (chunk * KBN) / KSPLIT;
    int kb1 = ((chunk + 1) * KBN) / KSPLIT;
    const unsigned short* Brow = p + ((size_t)(b * TP + w * 16 + lr)) * KP + 8 * lg;
    const unsigned short* Arow = w2p + (size_t)lr * KP + 8 * lg;
    f32x4 acc[5] = {};
    for (int kb = kb0; kb < kb1; kb++) {
        int ko = kb * 32;
        BF8 bf; bf.u = *(const u16x8*)(Brow + ko);
        #pragma unroll
        for (int mt = 0; mt < 5; mt++) {
            BF8 af; af.u = *(const u16x8*)(Arow + (size_t)mt * 16 * KP + ko);
            acc[mt] = __builtin_amdgcn_mfma_f32_16x16x32_bf16(af.b, bf.b, acc[mt], 0, 0, 0);
        }
    }
    float* pp = part + ((size_t)(chunk * BB + b) * WID) * TP;
    int t = w * 16 + lr;
    #pragma unroll
    for (int mt = 0; mt < 5; mt++) {
        int ob = mt * 16 + 4 * lg;
        #pragma unroll
        for (int r = 0; r < 4; r++)
            pp[(size_t)(ob + r) * TP + t] = acc[mt][r];
    }
}

// ---------------- reduce split-K + bn2 + elu (y2 stays in LDS) + proj -> z_bf ----------------
__global__ __launch_bounds__(256) void k_redproj(const float* __restrict__ part,
                                                 const float* __restrict__ scale2,
                                                 const float* __restrict__ shift2f,
                                                 const float* __restrict__ pw,
                                                 const float* __restrict__ pb,
                                                 unsigned short* __restrict__ zbf) {
    __shared__ float ly[WID * TP];   // 7680
    __shared__ float lw[EMB * WID];  // 640
    int b = blockIdx.x, tid = threadIdx.x;
    for (int i = tid; i < EMB * WID; i += 256) lw[i] = pw[i];
    for (int i = tid; i < WID * TP; i += 256) {
        float acc = 0.f;
        #pragma unroll
        for (int ks = 0; ks < KSPLIT; ks++)
            acc += part[(size_t)(ks * BB + b) * (WID * TP) + i];
        int o = i / TP;
        ly[i] = eluf(acc * scale2[o] + shift2f[o]);
    }
    __syncthreads();
    #pragma unroll
    for (int rep = 0; rep < 3; rep++) {
        int j = tid + 256 * rep;
        int e = j & 7, t = j >> 3;
        float acc = pb[e];
        #pragma unroll 10
        for (int o = 0; o < WID; o++) acc = fmaf(ly[o * TP + t], lw[e * WID + o], acc);
        zbf[(size_t)b * HID + j] = f2bf(acc);
    }
}

// ---------------- mlp1 batch-shared MFMA: z1[32,1024] = Zbf @ W1^T + b; g_bf = gelu(z1)
__global__ __launch_bounds__(256) void k_mlp1(const unsigned short* __restrict__ zbf,
                                              const float* __restrict__ w1,
                                              const float* __restrict__ bias,
                                              float* __restrict__ z1,
                                              unsigned short* __restrict__ gbf) {
    int n0 = blockIdx.x * 64;
    int tid = threadIdx.x, w = tid >> 6, lr = tid & 15, lg = (tid >> 4) & 3;
    int pcol = n0 + w * 16 + lr;
    const float* wr = w1 + (size_t)pcol * HID + 8 * lg;
    const unsigned short* za = zbf + (size_t)lr * HID + 8 * lg;
    f32x4 acc[2] = {};
    for (int kb = 0; kb < HID; kb += 32) {
        float4 w0 = *(const float4*)(wr + kb);
        float4 w1v = *(const float4*)(wr + kb + 4);
        BF8 bf;
        bf.u[0] = f2bf(w0.x); bf.u[1] = f2bf(w0.y); bf.u[2] = f2bf(w0.z); bf.u[3] = f2bf(w0.w);
        bf.u[4] = f2bf(w1v.x); bf.u[5] = f2bf(w1v.y); bf.u[6] = f2bf(w1v.z); bf.u[7] = f2bf(w1v.w);
        BF8 a0, a1;
        a0.u = *(const u16x8*)(za + kb);
        a1.u = *(const u16x8*)(za + (size_t)16 * HID + kb);
        acc[0] = __builtin_amdgcn_mfma_f32_16x16x32_bf16(a0.b, bf.b, acc[0], 0, 0, 0);
        acc[1] = __builtin_amdgcn_mfma_f32_16x16x32_bf16(a1.b, bf.b, acc[1], 0, 0, 0);
    }
    float bs = bias[pcol];
    #pragma unroll
    for (int mt = 0; mt < 2; mt++) {
        #pragma unroll
        for (int r = 0; r < 4; r++) {
            int bb = mt * 16 + 4 * lg + r;
            float v = acc[mt][r] + bs;
            z1[(size_t)bb * PROJ + pcol] = v;
            gbf[(size_t)bb * PROJ + pcol] = f2bf(0.5f * v * (1.f + erff(v * 0.70710678118654752f)));
        }
    }
}

// ---------------- mlp2 batch-shared MFMA + residual: y = z1 + Gbf @ W2^T + b2
__global__ __launch_bounds__(256) void k_mlp2(const unsigned short* __restrict__ gbf,
                                              const float* __restrict__ z1,
                                              const float* __restrict__ w2,
                                              const float* __restrict__ bias,
                                              float* __restrict__ y) {
    int n0 = blockIdx.x * 64;
    int tid = threadIdx.x, w = tid >> 6, lr = tid & 15, lg = (tid >> 4) & 3;
    int q = n0 + w * 16 + lr;
    const float* wr = w2 + (size_t)q * PROJ + 8 * lg;
    const unsigned short* ga = gbf + (size_t)lr * PROJ + 8 * lg;
    f32x4 acc[2] = {};
    for (int kb = 0; kb < PROJ; kb += 32) {
        float4 w0 = *(const float4*)(wr + kb);
        float4 w1v = *(const float4*)(wr + kb + 4);
        BF8 bf;
        bf.u[0] = f2bf(w0.x); bf.u[1] = f2bf(w0.y); bf.u[2] = f2bf(w0.z); bf.u[3] = f2bf(w0.w);
        bf.u[4] = f2bf(w1v.x); bf.u[5] = f2bf(w1v.y); bf.u[6] = f2bf(w1v.z); bf.u[7] = f2bf(w1v.w);
        BF8 a0, a1;
        a0.u = *(const u16x8*)(ga + kb);
        a1.u = *(const u16x8*)(ga + (size_t)16 * PROJ + kb);
        acc[0] = __builtin_amdgcn_mfma_f32_16x16x32_bf16(a0.b, bf.b, acc[0], 0, 0, 0);
        acc[1] = __builtin_amdgcn_mfma_f32_16x16x32_bf16(a1.b, bf.b, acc[1], 0, 0, 0);
    }
    float bs = bias[q];
    #pragma unroll
    for (int mt = 0; mt < 2; mt++) {
        #pragma unroll
        for (int r = 0; r < 4; r++) {
            int bb = mt * 16 + 4 * lg + r;
            y[(size_t)bb * PROJ + q] = z1[(size_t)bb * PROJ + q] + acc[mt][r] + bs;
        }
    }
}

// ---------------- LayerNorm over 1024 per row -> d_out
__global__ __launch_bounds__(256) void k_ln(const float* __restrict__ y,
                                            const float* __restrict__ lg,
                                            const float* __restrict__ lb,
                                            float* __restrict__ out) {
    int b = blockIdx.x, tid = threadIdx.x;
    const float4* yr = (const float4*)(y + (size_t)b * PROJ);
    float4 v = yr[tid];
    float s  = v.x + v.y + v.z + v.w;
    float sq = v.x*v.x + v.y*v.y + v.z*v.z + v.w*v.w;
    #pragma unroll
    for (int off = 32; off > 0; off >>= 1) {
        s  += __shfl_down(s, off);
        sq += __shfl_down(sq, off);
    }
    __shared__ float ss[4], ssq[4];
    int wv = tid >> 6, lane = tid & 63;
    if (lane == 0) { ss[wv] = s; ssq[wv] = sq; }
    __syncthreads();
    __shared__ float smu, sinv;
    if (tid == 0) {
        float Sm = ss[0] + ss[1] + ss[2] + ss[3];
        float Sq = ssq[0] + ssq[1] + ssq[2] + ssq[3];
        float mu = Sm * (1.f / PROJ);
        float var = Sq * (1.f / PROJ) - mu * mu;
        smu = mu;
        sinv = rsqrtf(var + EPSF);
    }
    __syncthreads();
    float mu = smu, inv = sinv;
    float4 g4 = ((const float4*)lg)[tid];
    float4 b4 = ((const float4*)lb)[tid];
    float4 o4;
    o4.x = (v.x - mu) * inv * g4.x + b4.x;
    o4.y = (v.y - mu) * inv * g4.y + b4.y;
    o4.z = (v.z - mu) * inv * g4.z + b4.z;
    o4.w = (v.w - mu) * inv * g4.w + b4.w;
    ((float4*)(out + (size_t)b * PROJ))[tid] = o4;
}

extern "C" void kernel_launch(void* const* d_in, const int* in_sizes, int n_in,
                              void* d_out, int out_size, void* d_ws, size_t ws_size,
                              hipStream_t stream) {
    const float* x        = (const float*)d_in[0];
    const int*   sid      = (const int*)  d_in[1];
    const float* W_sub    = (const float*)d_in[2];
    const float* b_sub    = (const float*)d_in[3];
    const float* conv1_w  = (const float*)d_in[4];
    const float* conv1_b  = (const float*)d_in[5];
    const float* bn1_g    = (const float*)d_in[6];
    const float* bn1_b    = (const float*)d_in[7];
    const float* bn1_m    = (const float*)d_in[8];
    const float* bn1_v    = (const float*)d_in[9];
    const float* conv2_w  = (const float*)d_in[10];
    const float* conv2_b  = (const float*)d_in[11];
    const float* bn2_g    = (const float*)d_in[12];
    const float* bn2_b    = (const float*)d_in[13];
    const float* bn2_m    = (const float*)d_in[14];
    const float* bn2_v    = (const float*)d_in[15];
    const float* proj_w   = (const float*)d_in[16];
    const float* proj_b   = (const float*)d_in[17];
    const float* mlp1_w   = (const float*)d_in[18];
    const float* mlp1_b   = (const float*)d_in[19];
    const float* mlp2_w   = (const float*)d_in[20];
    const float* mlp2_b   = (const float*)d_in[21];
    const float* ln_g     = (const float*)d_in[22];
    const float* ln_b     = (const float*)d_in[23];
    float* out = (float*)d_out;
    float* ws  = (float*)d_ws;

    float* ws_e    = ws + OFF_E;
    unsigned short* ws_xb  = (unsigned short*)(ws + OFF_XB);
    unsigned short* ws_wb  = (unsigned short*)(ws + OFF_WB);
    unsigned short* ws_w2p = (unsigned short*)(ws + OFF_W2P);
    unsigned short* ws_p   = (unsigned short*)(ws + OFF_P);
    float* ws_part = ws + OFF_PART;
    unsigned short* ws_zbf = (unsigned short*)(ws + OFF_Z);
    float* ws_z1   = ws + OFF_Z1;
    unsigned short* ws_gbf = (unsigned short*)(ws + OFF_G);
    float* ws_y    = ws + OFF_Y;
    unsigned short* ws_wcb = (unsigned short*)(ws + OFF_WCB);
    float* ws_b1f  = ws + OFF_B1F;
    float* ws_sc2  = ws + OFF_SC2;
    float* ws_sh2  = ws + OFF_SH2;

    hipLaunchKernelGGL(k_pack, dim3((NPK_TOT + 255) / 256), dim3(256), 0, stream,
                       x, W_sub, conv2_w,
                       conv1_w, conv1_b, bn1_g, bn1_b, bn1_m, bn1_v,
                       conv2_b, bn2_g, bn2_b, bn2_m, bn2_v,
                       ws_xb, ws_wb, ws_w2p,
                       ws_wcb, ws_b1f, ws_sc2, ws_sh2);

    hipLaunchKernelGGL(k_einsum, dim3(8, BB), dim3(256), 0, stream,
                       ws_xb, ws_wb, sid, b_sub, ws_e);

    hipLaunchKernelGGL(k_fir2, dim3(CC / 2, BB), dim3(256), 0, stream,
                       ws_e, ws_wcb, ws_b1f, ws_p);

    hipLaunchKernelGGL(k_conv2, dim3(KSPLIT, BB), dim3(384), 0, stream,
                       ws_p, ws_w2p, ws_part);

    hipLaunchKernelGGL(k_redproj, dim3(BB), dim3(256), 0, stream,
                       ws_part, ws_sc2, ws_sh2, proj_w, proj_b, ws_zbf);

    hipLaunchKernelGGL(k_mlp1, dim3(PROJ / 64), dim3(256), 0, stream,
                       ws_zbf, mlp1_w, mlp1_b, ws_z1, ws_gbf);

    hipLaunchKernelGGL(k_mlp2, dim3(PROJ / 64), dim3(256), 0, stream,
                       ws_gbf, ws_z1, mlp2_w, mlp2_b, ws_y);

    hipLaunchKernelGGL(k_ln, dim3(BB), dim3(256), 0, stream,
                       ws_y, ln_g, ln_b, out);
}